// Round 4
// baseline (210.430 us; speedup 1.0000x reference)
//
#include <hip/hip_runtime.h>
#include <hip/hip_bf16.h>
#include <math.h>

#define LTOT   4096
#define EDIM   64
#define NMODES 64
#define BH     256
#define TWO_PI 6.28318530717958647692f

typedef float f32x4 __attribute__((ext_vector_type(4)));
typedef short s16x8 __attribute__((ext_vector_type(8)));

__device__ inline unsigned short f2bf(float f) {
    unsigned u = __builtin_bit_cast(unsigned, f);
    u += 0x7fff + ((u >> 16) & 1);           // round-to-nearest-even
    return (unsigned short)(u >> 16);
}
// compiler-friendly pack: emits v_cvt_pk_bf16_f32
__device__ inline unsigned packbf(float lo, float hi) {
    float2 t; t.x = lo; t.y = hi;
    __hip_bfloat162 h = __float22bfloat162_rn(t);
    unsigned r;
    __builtin_memcpy(&r, &h, 4);
    return r;
}

// ---------- Tables ----------
// Tm[m=128][l=4096] bf16: Tm[2k][l]=cos, Tm[2k+1][l]=-sin  (forward DFT)
__global__ void k_tab_m(const int* __restrict__ index, unsigned short* __restrict__ Tm) {
    int k = blockIdx.x;
    int f = index[k];
    for (int l = threadIdx.x; l < LTOT; l += blockDim.x) {
        int m = (f * l) & (LTOT - 1);
        float th = (float)m * (TWO_PI / (float)LTOT);
        float s, c; sincosf(th, &s, &c);
        Tm[(size_t)(2 * k) * LTOT + l]     = f2bf(c);
        Tm[(size_t)(2 * k + 1) * LTOT + l] = f2bf(-s);
    }
}
// Tt[l=4096][m=128] bf16: Tt[l][2k]=cos, Tt[l][2k+1]=sin  (inverse DFT)
__global__ void k_tab_t(const int* __restrict__ index, unsigned short* __restrict__ Tt) {
    int l = blockIdx.x * 4 + (threadIdx.x >> 6);
    int k = threadIdx.x & 63;
    int f = index[k];
    int m = (f * l) & (LTOT - 1);
    float th = (float)m * (TWO_PI / (float)LTOT);
    float s, c; sincosf(th, &s, &c);
    ((unsigned*)Tt)[l * 64 + k] = packbf(c, s);
}

// ---------- Stage 1: X[e][m] = sum_l xT[e][l] * T[l][m]  (MFMA bf16) ----------
// grid = BH*4 (bh, quarter-of-L partial), 256 threads (4 waves, 2e-slices x 64modes each).
#define S1P32 36   // u32 pitch of xT rows (32 data + 4 pad)
__global__ __launch_bounds__(256) void k_stage1(const float* __restrict__ x,
                                                const unsigned short* __restrict__ Tm,
                                                float* __restrict__ Xp) {
    int bh = blockIdx.x >> 2, part = blockIdx.x & 3;
    const float* xb = x + (size_t)bh * LTOT * EDIM;
    __shared__ unsigned xT[64 * S1P32];           // [e=64][36 u32], XOR-swizzled

    int t = threadIdx.x;
    int q = t & 15, lp = t >> 4;                  // loader role
    int lane = t & 63, wave = t >> 6;             // mfma role
    int r = lane & 15, kb8 = lane >> 4;
    int esb = (wave & 1) * 2;                     // e-slice base (2 slices of 16 rows)
    int mb  = (wave >> 1) * 64;                   // mode-column base (64 per wave-pair)

    f32x4 acc[2][4];
    #pragma unroll
    for (int i = 0; i < 2; ++i)
        #pragma unroll
        for (int n = 0; n < 4; ++n) acc[i][n] = (f32x4)0.f;

    for (int tile = 0; tile < 16; ++tile) {
        int l0 = part * 1024 + tile * 64;
        __syncthreads();
        const float* b0 = xb + (size_t)(l0 + 2 * lp) * EDIM + 4 * q;
        float4 a0 = *(const float4*)(b0);
        float4 a1 = *(const float4*)(b0 + EDIM);
        float4 a2 = *(const float4*)(b0 + 32 * EDIM);
        float4 a3 = *(const float4*)(b0 + 33 * EDIM);
        float A0[4] = {a0.x, a0.y, a0.z, a0.w};
        float A1[4] = {a1.x, a1.y, a1.z, a1.w};
        float A2[4] = {a2.x, a2.y, a2.z, a2.w};
        float A3[4] = {a3.x, a3.y, a3.z, a3.w};
        #pragma unroll
        for (int j = 0; j < 4; ++j) {
            int e = 4 * q + j;
            unsigned v = ((unsigned)(e >> 2) & 7u) << 2;           // = (q&7)<<2
            xT[e * S1P32 + (( (unsigned)lp      ) ^ v)] = packbf(A0[j], A1[j]);  // l 2lp,2lp+1
            xT[e * S1P32 + (( (unsigned)lp + 16u) ^ v)] = packbf(A2[j], A3[j]);  // l 2lp+32,+33
        }
        __syncthreads();
        #pragma unroll
        for (int kk = 0; kk < 2; ++kk) {
            s16x8 bf[4];
            #pragma unroll
            for (int ns = 0; ns < 4; ++ns) {
                int m = mb + ns * 16 + r;
                bf[ns] = *(const s16x8*)(Tm + (size_t)m * LTOT + (l0 + kk * 32 + kb8 * 8));
            }
            #pragma unroll
            for (int es = 0; es < 2; ++es) {
                int e = (esb + es) * 16 + r;
                unsigned v = ((unsigned)(e >> 2) & 7u) << 2;
                const unsigned* rowp = xT + e * S1P32;
                s16x8 af = *(const s16x8*)(rowp + (((unsigned)(kk * 16 + kb8 * 4)) ^ v));
                #pragma unroll
                for (int ns = 0; ns < 4; ++ns)
                    acc[es][ns] = __builtin_amdgcn_mfma_f32_16x16x32_bf16(af, bf[ns], acc[es][ns], 0, 0, 0);
            }
        }
    }
    float* Xb = Xp + ((size_t)part * BH + bh) * (64 * 128);
    #pragma unroll
    for (int es = 0; es < 2; ++es)
        #pragma unroll
        for (int ns = 0; ns < 4; ++ns)
            #pragma unroll
            for (int g = 0; g < 4; ++g) {
                int e = (esb + es) * 16 + kb8 * 4 + g;   // C/D: row=(lane>>4)*4+reg
                int m = mb + ns * 16 + r;                //      col=lane&15
                Xb[e * 128 + m] = acc[es][ns][g];
            }
}

// ---------- Stage 2: mode mix + irfft coeff prep ----------
// grid = 128 (2 bh each), 512 threads.
// Output ABo[bh][o=64][k=64] u32: lo16 = bf16(cc*Re) (cos coeff), hi16 = bf16(-cc*Im) (sin coeff)
__global__ __launch_bounds__(512) void k_stage2(const float* __restrict__ Xp,
                                                const float2* __restrict__ w2,
                                                const int* __restrict__ index,
                                                unsigned* __restrict__ ABo) {
    int bh0 = blockIdx.x * 2;
    __shared__ float Xs[2][64 * 128];   // 64 KB
    int t = threadIdx.x;

    #pragma unroll
    for (int bhi = 0; bhi < 2; ++bhi) {
        f32x4 a[4];
        #pragma unroll
        for (int i = 0; i < 4; ++i) a[i] = (f32x4)0.f;
        #pragma unroll
        for (int p = 0; p < 4; ++p) {
            const f32x4* src = (const f32x4*)(Xp + ((size_t)p * BH + bh0 + bhi) * 8192);
            #pragma unroll
            for (int i = 0; i < 4; ++i) a[i] += src[t + i * 512];
        }
        f32x4* dst = (f32x4*)Xs[bhi];
        #pragma unroll
        for (int i = 0; i < 4; ++i) dst[t + i * 512] = a[i];
    }
    __syncthreads();

    int k = t & 63, og = t >> 6;     // og 0..7 -> 8 outputs each
    int f = index[k];
    float cc = (f == 0 ? 1.0f : 2.0f) / (float)LTOT;
    float aR[2][8] = {}, aI[2][8] = {};
    for (int e = 0; e < 64; ++e) {
        float2 X0 = *(const float2*)&Xs[0][e * 128 + 2 * k];
        float2 X1 = *(const float2*)&Xs[1][e * 128 + 2 * k];
        #pragma unroll
        for (int oi = 0; oi < 8; ++oi) {
            int o = og * 8 + oi;
            float2 wv = w2[((size_t)e * 64 + o) * 64 + k];   // w is [e][o][k] float2 natively
            aR[0][oi] += X0.x * wv.x - X0.y * wv.y;
            aI[0][oi] += X0.x * wv.y + X0.y * wv.x;
            aR[1][oi] += X1.x * wv.x - X1.y * wv.y;
            aI[1][oi] += X1.x * wv.y + X1.y * wv.x;
        }
    }
    #pragma unroll
    for (int bhi = 0; bhi < 2; ++bhi)
        #pragma unroll
        for (int oi = 0; oi < 8; ++oi) {
            int o = og * 8 + oi;
            float im = (f == 0) ? 0.0f : -cc * aI[bhi][oi];
            ABo[((size_t)(bh0 + bhi) * 64 + o) * 64 + k] = packbf(cc * aR[bhi][oi], im);
        }
}

// ---------- Stage 3: y[l][o] = sum_m AB[o][m] * Tt[l][m]  (MFMA, A=coeffs reg-cached) ----------
// grid = BH*4 (bh, quarter of L), 256 threads (4 waves).
#define S3P16 136   // u16 pitch of ABl rows
__global__ __launch_bounds__(256) void k_stage3(const unsigned short* __restrict__ Tt,
                                                const unsigned* __restrict__ ABo,
                                                float* __restrict__ y) {
    int bh = blockIdx.x >> 2, qtr = blockIdx.x & 3;
    __shared__ unsigned short ABl[64 * S3P16];   // [o=64][128 bf16 + 8 pad]
    int t = threadIdx.x;
    int lane = t & 63, wave = t >> 6;
    int r = lane & 15, kb8 = lane >> 4;

    {   // load ABo[bh] (64o x 64 u32) into LDS with padded pitch
        const unsigned* src = ABo + (size_t)bh * 4096;
        unsigned* dst = (unsigned*)ABl;
        #pragma unroll
        for (int i = 0; i < 16; ++i) {
            int idx = t + i * 256;             // over [64 o][64 u32]
            int o = idx >> 6, c = idx & 63;
            dst[o * (S3P16 / 2) + c] = src[idx];
        }
    }
    __syncthreads();

    // register-cache A-fragments: afr[es][ks], row o = es*16 + r, m-chunk ks*32 + kb8*8
    s16x8 afr[4][4];
    #pragma unroll
    for (int es = 0; es < 4; ++es)
        #pragma unroll
        for (int ks = 0; ks < 4; ++ks)
            afr[es][ks] = *(const s16x8*)(ABl + (es * 16 + r) * S3P16 + ks * 32 + kb8 * 8);

    for (int it = 0; it < 16; ++it) {
        int ltile = qtr * 1024 + it * 64 + wave * 16;
        s16x8 btf[4];
        #pragma unroll
        for (int ks = 0; ks < 4; ++ks)       // B-frag: col l = ltile + r, k = m contiguous
            btf[ks] = *(const s16x8*)(Tt + (size_t)(ltile + r) * 128 + ks * 32 + kb8 * 8);
        f32x4 acc[4];
        #pragma unroll
        for (int es = 0; es < 4; ++es) acc[es] = (f32x4)0.f;
        #pragma unroll
        for (int ks = 0; ks < 4; ++ks)
            #pragma unroll
            for (int es = 0; es < 4; ++es)
                acc[es] = __builtin_amdgcn_mfma_f32_16x16x32_bf16(afr[es][ks], btf[ks], acc[es], 0, 0, 0);
        // D: row = o = es*16 + kb8*4 + g, col = l = ltile + r  ->  f32x4 store along o
        float* yb = y + ((size_t)bh * LTOT + ltile + r) * EDIM;
        #pragma unroll
        for (int es = 0; es < 4; ++es)
            *(f32x4*)(yb + es * 16 + kb8 * 4) = acc[es];
    }
}

extern "C" void kernel_launch(void* const* d_in, const int* in_sizes, int n_in,
                              void* d_out, int out_size, void* d_ws, size_t ws_size,
                              hipStream_t stream) {
    const float* x     = (const float*)d_in[0];
    const float* w     = (const float*)d_in[1];
    const int*   index = (const int*)d_in[2];
    float* y  = (float*)d_out;
    float* ws = (float*)d_ws;

    // ws layout (float offsets): Tm 1MB | Tt 1MB | Xp 33.5MB | ABo 4MB
    unsigned short* Tm = (unsigned short*)ws;
    unsigned short* Tt = (unsigned short*)(ws + 262144);
    float*          Xp = ws + 524288;
    unsigned*       ABo = (unsigned*)(ws + 8912896);

    hipLaunchKernelGGL(k_tab_m,  dim3(NMODES), dim3(256), 0, stream, index, Tm);
    hipLaunchKernelGGL(k_tab_t,  dim3(1024),   dim3(256), 0, stream, index, Tt);
    hipLaunchKernelGGL(k_stage1, dim3(BH * 4), dim3(256), 0, stream, x, Tm, Xp);
    hipLaunchKernelGGL(k_stage2, dim3(BH / 2), dim3(512), 0, stream, Xp, (const float2*)w, index, ABo);
    hipLaunchKernelGGL(k_stage3, dim3(BH * 4), dim3(256), 0, stream, Tt, ABo, y);
}